// Round 14
// baseline (614.138 us; speedup 1.0000x reference)
//
#include <hip/hip_runtime.h>

#define N_NODES_C 100000
#define N_EDGES_C 1200000
#define NUM_GRAPHS_C 64
#define D_C 64
#define CAP_C 64
#define NPASS_C 8
#define BN_EPS_C 1e-5f

typedef unsigned short u16;
typedef unsigned int u32;

using frag_ab = __attribute__((ext_vector_type(8))) short;  // 8 bf16 (4 VGPRs)
using f32x4   = __attribute__((ext_vector_type(4))) float;

__device__ __forceinline__ u16 f2bf(float f) {  // RTNE
    u32 x = __float_as_uint(f);
    x += 0x7fffu + ((x >> 16) & 1u);
    return (u16)(x >> 16);
}
__device__ __forceinline__ float bf2f(u16 u) {
    return __uint_as_float(((u32)u) << 16);
}

// ------------- XCD-swizzled bucket scatter + W-prep (last block) ----------
// pass = blockIdx&7 -> XCD-local dst range: dirty bucket lines stay in that
// XCD's 4 MB L2, writes retire once (R10-proven: killed the 72 MB write
// amplification). Last block converts W1/W2 to bf16 [n][k].
__global__ void __launch_bounds__(256) k_scatter(
        const int* __restrict__ src, const int* __restrict__ dst,
        int* __restrict__ cnt, int* __restrict__ col,
        const float* __restrict__ W1, const float* __restrict__ W2,
        u16* __restrict__ Wb1, u16* __restrict__ Wb2) {
    int nsc = gridDim.x - 1;
    if ((int)blockIdx.x == nsc) {  // W prep: 4096 elems each
        for (int i = threadIdx.x; i < 4096; i += 256) {
            int n = i >> 6, k = i & 63;
            Wb1[i] = f2bf(W1[k * 64 + n]);
            Wb2[i] = f2bf(W2[k * 64 + n]);
        }
        return;
    }
    int pass = blockIdx.x & (NPASS_C - 1);
    int chunk = blockIdx.x >> 3;
    int nchunks = nsc >> 3;
    const int RANGE = N_NODES_C / NPASS_C;  // 12500
    int lo = pass * RANGE;
    int hi = (pass == NPASS_C - 1) ? N_NODES_C : lo + RANGE;
    const int nquads = N_EDGES_C / 4;  // 300000
    int tid = chunk * 256 + threadIdx.x;
    int nthreads = nchunks * 256;
    const int4* dst4 = (const int4*)dst;
    const int4* src4 = (const int4*)src;
    for (int i = tid; i < nquads; i += nthreads) {
        int4 d4 = dst4[i];
        int dd[4] = {d4.x, d4.y, d4.z, d4.w};
        bool in0 = dd[0] >= lo && dd[0] < hi;
        bool in1 = dd[1] >= lo && dd[1] < hi;
        bool in2 = dd[2] >= lo && dd[2] < hi;
        bool in3 = dd[3] >= lo && dd[3] < hi;
        if (in0 | in1 | in2 | in3) {
            int4 s4 = src4[i];
            int ss[4] = {s4.x, s4.y, s4.z, s4.w};
            bool in[4] = {in0, in1, in2, in3};
#pragma unroll
            for (int k = 0; k < 4; ++k) {
                if (in[k]) {
                    int pos = atomicAdd(&cnt[dd[k]], 1);
                    if (pos < CAP_C) col[(size_t)dd[k] * CAP_C + pos] = ss[k];
                }
            }
        }
    }
}

// ------------------- GEMM via MFMA 16x16x32 bf16 --------------------------
// T node-major bf16, dinv[row] folded. gemm1 reads fp32 x with inline
// bf16 convert (no Xb prep pass); gemm2 reads bf16 Ab node-major.
template <bool A_FP32>
__device__ __forceinline__ void gemm_body(
        const void* __restrict__ Xa, const u16* __restrict__ Wb,
        const int* __restrict__ cnt, u16* __restrict__ T) {
    int lane = threadIdx.x & 63;
    int q = lane >> 4, ln = lane & 15;
    int wave = blockIdx.x * 4 + (threadIdx.x >> 6);
    int nwaves = gridDim.x * 4;
    frag_ab bfr[4][2];
#pragma unroll
    for (int nt = 0; nt < 4; ++nt)
#pragma unroll
        for (int kh = 0; kh < 2; ++kh)
            bfr[nt][kh] = *(const frag_ab*)(Wb + (nt * 16 + ln) * 64 + kh * 32 + q * 8);
    const int nstrips = N_NODES_C / 16;
    for (int s = wave; s < nstrips; s += nwaves) {
        int r0 = s * 16;
        frag_ab a0, a1;
        if (A_FP32) {
            const float* xr = (const float*)Xa + (size_t)(r0 + ln) * 64;
            float4 x0 = *(const float4*)(xr + q * 8);
            float4 x1 = *(const float4*)(xr + q * 8 + 4);
            float4 x2 = *(const float4*)(xr + 32 + q * 8);
            float4 x3 = *(const float4*)(xr + 32 + q * 8 + 4);
            a0[0]=(short)f2bf(x0.x); a0[1]=(short)f2bf(x0.y);
            a0[2]=(short)f2bf(x0.z); a0[3]=(short)f2bf(x0.w);
            a0[4]=(short)f2bf(x1.x); a0[5]=(short)f2bf(x1.y);
            a0[6]=(short)f2bf(x1.z); a0[7]=(short)f2bf(x1.w);
            a1[0]=(short)f2bf(x2.x); a1[1]=(short)f2bf(x2.y);
            a1[2]=(short)f2bf(x2.z); a1[3]=(short)f2bf(x2.w);
            a1[4]=(short)f2bf(x3.x); a1[5]=(short)f2bf(x3.y);
            a1[6]=(short)f2bf(x3.z); a1[7]=(short)f2bf(x3.w);
        } else {
            const u16* xr = (const u16*)Xa + (size_t)(r0 + ln) * 64;
            a0 = *(const frag_ab*)(xr + q * 8);
            a1 = *(const frag_ab*)(xr + 32 + q * 8);
        }
        f32x4 acc[4];
#pragma unroll
        for (int nt = 0; nt < 4; ++nt) {
            acc[nt] = (f32x4){0.f, 0.f, 0.f, 0.f};
            acc[nt] = __builtin_amdgcn_mfma_f32_16x16x32_bf16(a0, bfr[nt][0], acc[nt], 0, 0, 0);
            acc[nt] = __builtin_amdgcn_mfma_f32_16x16x32_bf16(a1, bfr[nt][1], acc[nt], 0, 0, 0);
        }
        float di[4];
#pragma unroll
        for (int reg = 0; reg < 4; ++reg)
            di[reg] = rsqrtf((float)(cnt[r0 + q * 4 + reg] + 1));
#pragma unroll
        for (int nt = 0; nt < 4; ++nt)
#pragma unroll
            for (int reg = 0; reg < 4; ++reg)
                T[(size_t)(r0 + q * 4 + reg) * 64 + nt * 16 + ln] =
                    f2bf(acc[nt][reg] * di[reg]);
    }
}

__global__ void __launch_bounds__(256) k_gemm1(
        const float* __restrict__ X, const u16* __restrict__ Wb,
        const int* __restrict__ cnt, u16* __restrict__ T) {
    gemm_body<true>(X, Wb, cnt, T);
}
__global__ void __launch_bounds__(256) k_gemm2(
        const u16* __restrict__ Ab, const u16* __restrict__ Wb,
        const int* __restrict__ cnt, u16* __restrict__ T) {
    gemm_body<false>(Ab, Wb, cnt, T);
}

// ------------- gather: 8 rows per load instruction (group=node) -----------
// R5-R13 plateau diagnosis: every variant issued ~1 vmem instruction per
// edge (~1.2M/layer) and landed 92-107 us -> instruction/TA-rate bound.
// Here wave = 8 groups x 8 sublanes; a single dwordx4 load fetches 8 FULL
// 128 B bf16 rows (one per group) = 8 edges/instruction. Lane accumulates
// its 8 features in fp32 -> group's 64 features complete, zero shuffles
// (R12). All per-lane arrays <=4 elems, constant-indexed (spill-safe).
__device__ __forceinline__ void row_add(uint4 w, bool valid,
                                        float aL[4], float aH[4]) {
    aL[0] += valid ? __uint_as_float(w.x << 16) : 0.f;
    aH[0] += valid ? __uint_as_float(w.x & 0xffff0000u) : 0.f;
    aL[1] += valid ? __uint_as_float(w.y << 16) : 0.f;
    aH[1] += valid ? __uint_as_float(w.y & 0xffff0000u) : 0.f;
    aL[2] += valid ? __uint_as_float(w.z << 16) : 0.f;
    aH[2] += valid ? __uint_as_float(w.z & 0xffff0000u) : 0.f;
    aL[3] += valid ? __uint_as_float(w.w << 16) : 0.f;
    aH[3] += valid ? __uint_as_float(w.w & 0xffff0000u) : 0.f;
}

template <bool POOL>
__device__ __forceinline__ void gather_body(
        const u16* __restrict__ T, const int* __restrict__ col,
        const int* __restrict__ cnt,
        const float* __restrict__ b, const float* __restrict__ g,
        const float* __restrict__ be, const float* __restrict__ m,
        const float* __restrict__ v, const int* __restrict__ batch,
        u16* __restrict__ Ab, float* __restrict__ pooled) {
    int lane = threadIdx.x & 63;
    int grp = lane >> 3;  // group 0..7, one node at a time
    int sub = lane & 7;   // 8 features: f = sub*8 + (2d, 2d+1)
    int wave = blockIdx.x * 4 + (threadIdx.x >> 6);
    int nwaves = gridDim.x * 4;
    int gid = wave * 8 + grp;
    int ngroups = nwaves * 8;
    const int chunk = (N_NODES_C + ngroups - 1) / ngroups;
    int r0 = gid * chunk;
    int r1 = r0 + chunk; if (r1 > N_NODES_C) r1 = N_NODES_C;
    float scL[4], scH[4], cL[4], cH[4];
#pragma unroll
    for (int d = 0; d < 4; ++d) {
        int fL = sub * 8 + 2 * d, fH = fL + 1;
        scL[d] = g[fL] * rsqrtf(v[fL] + BN_EPS_C);
        cL[d]  = (b[fL] - m[fL]) * scL[d] + be[fL];
        scH[d] = g[fH] * rsqrtf(v[fH] + BN_EPS_C);
        cH[d]  = (b[fH] - m[fH]) * scH[d] + be[fH];
    }
    float pL[4] = {0.f,0.f,0.f,0.f}, pH[4] = {0.f,0.f,0.f,0.f};
    int curg = -1;
    for (int r = r0; r < r1; ++r) {
        int deg = cnt[r]; if (deg > CAP_C) deg = CAP_C;
        const int* cb = col + (size_t)r * CAP_C;
        uint4 s = *(const uint4*)(T + (size_t)r * 64 + sub * 8);
        float aL[4], aH[4];
        aL[0] = __uint_as_float(s.x << 16); aH[0] = __uint_as_float(s.x & 0xffff0000u);
        aL[1] = __uint_as_float(s.y << 16); aH[1] = __uint_as_float(s.y & 0xffff0000u);
        aL[2] = __uint_as_float(s.z << 16); aH[2] = __uint_as_float(s.z & 0xffff0000u);
        aL[3] = __uint_as_float(s.w << 16); aH[3] = __uint_as_float(s.w & 0xffff0000u);
        for (int j = 0; j < deg; j += 4) {
            int4 c4 = *(const int4*)(cb + j);  // in-bounds: CAP=64
            int i0 = (j + 0 < deg) ? c4.x : r;
            int i1 = (j + 1 < deg) ? c4.y : r;
            int i2 = (j + 2 < deg) ? c4.z : r;
            int i3 = (j + 3 < deg) ? c4.w : r;
            uint4 w0 = *(const uint4*)(T + (size_t)i0 * 64 + sub * 8);
            uint4 w1 = *(const uint4*)(T + (size_t)i1 * 64 + sub * 8);
            uint4 w2 = *(const uint4*)(T + (size_t)i2 * 64 + sub * 8);
            uint4 w3 = *(const uint4*)(T + (size_t)i3 * 64 + sub * 8);
            row_add(w0, j + 0 < deg, aL, aH);
            row_add(w1, j + 1 < deg, aL, aH);
            row_add(w2, j + 2 < deg, aL, aH);
            row_add(w3, j + 3 < deg, aL, aH);
        }
        float dr = rsqrtf((float)(deg + 1));
        float oL[4], oH[4];
#pragma unroll
        for (int d = 0; d < 4; ++d) {
            oL[d] = fmaxf(fmaf(aL[d] * dr, scL[d], cL[d]), 0.f);
            oH[d] = fmaxf(fmaf(aH[d] * dr, scH[d], cH[d]), 0.f);
        }
        if (POOL) {
            int gb = batch[r];
            if (gb != curg) {
                if (curg >= 0) {
#pragma unroll
                    for (int d = 0; d < 4; ++d) {
                        atomicAdd(&pooled[curg * 64 + sub * 8 + 2 * d], pL[d]);
                        atomicAdd(&pooled[curg * 64 + sub * 8 + 2 * d + 1], pH[d]);
                    }
                }
                curg = gb;
#pragma unroll
                for (int d = 0; d < 4; ++d) { pL[d] = 0.f; pH[d] = 0.f; }
            }
#pragma unroll
            for (int d = 0; d < 4; ++d) { pL[d] += oL[d]; pH[d] += oH[d]; }
        } else {
            uint4 o;
            o.x = (u32)f2bf(oL[0]) | ((u32)f2bf(oH[0]) << 16);
            o.y = (u32)f2bf(oL[1]) | ((u32)f2bf(oH[1]) << 16);
            o.z = (u32)f2bf(oL[2]) | ((u32)f2bf(oH[2]) << 16);
            o.w = (u32)f2bf(oL[3]) | ((u32)f2bf(oH[3]) << 16);
            *(uint4*)(Ab + (size_t)r * 64 + sub * 8) = o;
        }
    }
    if (POOL && curg >= 0) {
#pragma unroll
        for (int d = 0; d < 4; ++d) {
            atomicAdd(&pooled[curg * 64 + sub * 8 + 2 * d], pL[d]);
            atomicAdd(&pooled[curg * 64 + sub * 8 + 2 * d + 1], pH[d]);
        }
    }
}

__global__ void __launch_bounds__(256) k_gather1(
        const u16* __restrict__ T, const int* __restrict__ col,
        const int* __restrict__ cnt,
        const float* __restrict__ b, const float* __restrict__ g,
        const float* __restrict__ be, const float* __restrict__ m,
        const float* __restrict__ v, u16* __restrict__ Ab) {
    gather_body<false>(T, col, cnt, b, g, be, m, v, nullptr, Ab, nullptr);
}

__global__ void __launch_bounds__(256) k_gather2(
        const u16* __restrict__ T, const int* __restrict__ col,
        const int* __restrict__ cnt,
        const float* __restrict__ b, const float* __restrict__ g,
        const float* __restrict__ be, const float* __restrict__ m,
        const float* __restrict__ v, const int* __restrict__ batch,
        float* __restrict__ pooled) {
    gather_body<true>(T, col, cnt, b, g, be, m, v, batch, nullptr, pooled);
}

// ----------------------------- classifier --------------------------------
__global__ void k_final(const float* __restrict__ pooled, const int* __restrict__ batch,
                        const float* __restrict__ Wc, const float* __restrict__ bc,
                        float* __restrict__ out) {
    __shared__ float sp[64 * 65];
    __shared__ int sub[64];
    int t = threadIdx.x;  // 256 threads
    for (int i = t; i < 4096; i += 256) sp[(i >> 6) * 65 + (i & 63)] = pooled[i];
    if (t < 64) {
        int lo = 0, hi = N_NODES_C;
        while (lo < hi) { int mid = (lo + hi) >> 1; if (batch[mid] > t) hi = mid; else lo = mid + 1; }
        sub[t] = lo;  // first index with batch > t
    }
    __syncthreads();
    if (t < 64) {
        int gi = t;
        int lb = gi ? sub[gi - 1] : 0;
        int cntg = sub[gi] - lb;
        float inv = 1.0f / fmaxf((float)cntg, 1.0f);
        float a0 = 0.f, a1 = 0.f;
#pragma unroll 8
        for (int f = 0; f < 64; ++f) {
            float p = sp[gi * 65 + f];
            a0 = fmaf(p, Wc[f * 2 + 0], a0);
            a1 = fmaf(p, Wc[f * 2 + 1], a1);
        }
        out[gi * 2 + 0] = a0 * inv + bc[0];
        out[gi * 2 + 1] = a1 * inv + bc[1];
    }
}

extern "C" void kernel_launch(void* const* d_in, const int* in_sizes, int n_in,
                              void* d_out, int out_size, void* d_ws, size_t ws_size,
                              hipStream_t stream) {
    const float* x    = (const float*)d_in[0];
    const int*   ei   = (const int*)d_in[1];
    const int*   batch= (const int*)d_in[2];
    const float* W1 = (const float*)d_in[3];
    const float* b1 = (const float*)d_in[4];
    const float* g1 = (const float*)d_in[5];
    const float* be1= (const float*)d_in[6];
    const float* m1 = (const float*)d_in[7];
    const float* v1 = (const float*)d_in[8];
    const float* W2 = (const float*)d_in[9];
    const float* b2 = (const float*)d_in[10];
    const float* g2 = (const float*)d_in[11];
    const float* be2= (const float*)d_in[12];
    const float* m2 = (const float*)d_in[13];
    const float* v2 = (const float*)d_in[14];
    const float* Wc = (const float*)d_in[15];
    const float* bc = (const float*)d_in[16];
    float* out = (float*)d_out;

    char* ws = (char*)d_ws;
    size_t off = 0;
    auto alloc = [&](size_t bytes) {
        size_t o = off;
        off = (off + bytes + 511) & ~(size_t)511;
        return o;
    };
    size_t o_cnt   = alloc((size_t)N_NODES_C * 4);
    size_t o_pool  = alloc((size_t)NUM_GRAPHS_C * D_C * 4);
    size_t zero_bytes = off;  // [cnt | pooled] zeroed each call
    size_t o_col   = alloc((size_t)N_NODES_C * CAP_C * 4 + 1024);
    size_t o_wb1   = alloc(4096 * 2);
    size_t o_wb2   = alloc(4096 * 2);
    size_t o_t     = alloc((size_t)N_NODES_C * D_C * 2);  // bf16 node-major
    size_t o_ab    = alloc((size_t)N_NODES_C * D_C * 2);  // bf16 node-major
    (void)ws_size; (void)in_sizes; (void)n_in; (void)out_size;

    int*   cnt    = (int*)(ws + o_cnt);
    float* pooled = (float*)(ws + o_pool);
    int*   col    = (int*)(ws + o_col);
    u16*   Wb1    = (u16*)(ws + o_wb1);
    u16*   Wb2    = (u16*)(ws + o_wb2);
    u16*   T      = (u16*)(ws + o_t);
    u16*   Ab     = (u16*)(ws + o_ab);

    const int* srcp = ei;
    const int* dstp = ei + N_EDGES_C;

    hipMemsetAsync(ws, 0, zero_bytes, stream);

    int sblocks = 2048 + 1;  // 256 chunks x 8 XCD ranges + 1 W-prep block
    int gblocks = 1568;      // 6272 waves -> 50176 groups, chunk=2
    int mblocks = 1563;      // 6252 waves: one 16-row strip each
    k_scatter<<<sblocks, 256, 0, stream>>>(srcp, dstp, cnt, col, W1, W2, Wb1, Wb2);

    k_gemm1<<<mblocks, 256, 0, stream>>>(x, Wb1, cnt, T);
    k_gather1<<<gblocks, 256, 0, stream>>>(T, col, cnt, b1, g1, be1, m1, v1, Ab);
    k_gemm2<<<mblocks, 256, 0, stream>>>(Ab, Wb2, cnt, T);
    k_gather2<<<gblocks, 256, 0, stream>>>(T, col, cnt, b2, g2, be2, m2, v2,
                                           batch, pooled);
    k_final<<<1, 256, 0, stream>>>(pooled, batch, Wc, bc, out);
}

// Round 15
// 425.229 us; speedup vs baseline: 1.4443x; 1.4443x over previous
//
#include <hip/hip_runtime.h>

#define N_NODES_C 100000
#define N_EDGES_C 1200000
#define NUM_GRAPHS_C 64
#define D_C 64
#define CAP_C 64
#define NPASS_C 8
#define RANGE_C 12500
#define CAPSEG_C 160000
#define BN_EPS_C 1e-5f

typedef unsigned short u16;
typedef unsigned int u32;

using frag_ab = __attribute__((ext_vector_type(8))) short;  // 8 bf16 (4 VGPRs)
using f32x4   = __attribute__((ext_vector_type(4))) float;

__device__ __forceinline__ u16 f2bf(float f) {  // RTNE
    u32 x = __float_as_uint(f);
    x += 0x7fffu + ((x >> 16) & 1u);
    return (u16)(x >> 16);
}
__device__ __forceinline__ float bf2f(u16 u) {
    return __uint_as_float(((u32)u) << 16);
}

// ------------- phase A: partition edges by dst range (+ W prep) -----------
// One pass over edges; LDS histogram + global cursor reservation appends
// (src,dst) densely into 8 dst-range segments (coalesced 8 B writes).
// Replaces R10's 8x edge-stream re-read (~77 MB) with 1x read + 1x write.
// Last block converts W1/W2 to bf16 [n][k].
__global__ void __launch_bounds__(256) k_part(
        const int* __restrict__ src, const int* __restrict__ dst,
        int* __restrict__ gcur, int2* __restrict__ seg,
        const float* __restrict__ W1, const float* __restrict__ W2,
        u16* __restrict__ Wb1, u16* __restrict__ Wb2) {
    int nblk = gridDim.x - 1;
    if ((int)blockIdx.x == nblk) {
        for (int i = threadIdx.x; i < 4096; i += 256) {
            int n = i >> 6, k = i & 63;
            Wb1[i] = f2bf(W1[k * 64 + n]);
            Wb2[i] = f2bf(W2[k * 64 + n]);
        }
        return;
    }
    __shared__ int lcnt[8];
    __shared__ int lbase[8];
    int t = threadIdx.x;
    for (int base = blockIdx.x * 256; base < N_EDGES_C; base += nblk * 256) {
        int e = base + t;
        bool valid = e < N_EDGES_C;
        int s = 0, d = 0, r = 0;
        if (valid) { s = src[e]; d = dst[e]; r = d / RANGE_C; if (r > 7) r = 7; }
        if (t < 8) lcnt[t] = 0;
        __syncthreads();
        int rank = 0;
        if (valid) rank = atomicAdd(&lcnt[r], 1);
        __syncthreads();
        if (t < 8) lbase[t] = atomicAdd(&gcur[t], lcnt[t]);
        __syncthreads();
        if (valid) {
            int idx = lbase[r] + rank;
            if (idx < CAPSEG_C)  // statistically impossible overflow; mem safety
                seg[(size_t)r * CAPSEG_C + idx] = make_int2(s, d);
        }
        __syncthreads();  // protect lcnt reuse
    }
}

// ------------- phase B: L2-local bucket build -----------------------------
// pass = blockIdx&7 -> XCD p (R10-validated). Blocks of pass p read only
// segment p (sequential ~1.2 MB) and scatter into cnt/col for dst range p:
// cnt lines (50 KB) and dirty bucket lines (~1.6 MB) stay in that XCD's L2.
__global__ void __launch_bounds__(256) k_bucket(
        const int2* __restrict__ seg, const int* __restrict__ gcur,
        int* __restrict__ cnt, int* __restrict__ col) {
    int pass = blockIdx.x & 7;
    int chunk = blockIdx.x >> 3;
    int nchunks = gridDim.x >> 3;
    int n = gcur[pass]; if (n > CAPSEG_C) n = CAPSEG_C;
    const int2* sp = seg + (size_t)pass * CAPSEG_C;
    for (int i = chunk * 256 + threadIdx.x; i < n; i += nchunks * 256) {
        int2 e = sp[i];
        int pos = atomicAdd(&cnt[e.y], 1);
        if (pos < CAP_C) col[(size_t)e.y * CAP_C + pos] = e.x;
    }
}

// ------------------- GEMM via MFMA 16x16x32 bf16 --------------------------
// T node-major bf16, dinv[row] = rsqrt(cnt+1) folded. gemm1 reads fp32 x
// with inline bf16 convert (R14-proven; no prep pass); gemm2 reads bf16 Ab.
template <bool A_FP32>
__device__ __forceinline__ void gemm_body(
        const void* __restrict__ Xa, const u16* __restrict__ Wb,
        const int* __restrict__ cnt, u16* __restrict__ T) {
    int lane = threadIdx.x & 63;
    int q = lane >> 4, ln = lane & 15;
    int wave = blockIdx.x * 4 + (threadIdx.x >> 6);
    int nwaves = gridDim.x * 4;
    frag_ab bfr[4][2];
#pragma unroll
    for (int nt = 0; nt < 4; ++nt)
#pragma unroll
        for (int kh = 0; kh < 2; ++kh)
            bfr[nt][kh] = *(const frag_ab*)(Wb + (nt * 16 + ln) * 64 + kh * 32 + q * 8);
    const int nstrips = N_NODES_C / 16;
    for (int s = wave; s < nstrips; s += nwaves) {
        int r0 = s * 16;
        frag_ab a0, a1;
        if (A_FP32) {
            const float* xr = (const float*)Xa + (size_t)(r0 + ln) * 64;
            float4 x0 = *(const float4*)(xr + q * 8);
            float4 x1 = *(const float4*)(xr + q * 8 + 4);
            float4 x2 = *(const float4*)(xr + 32 + q * 8);
            float4 x3 = *(const float4*)(xr + 32 + q * 8 + 4);
            a0[0]=(short)f2bf(x0.x); a0[1]=(short)f2bf(x0.y);
            a0[2]=(short)f2bf(x0.z); a0[3]=(short)f2bf(x0.w);
            a0[4]=(short)f2bf(x1.x); a0[5]=(short)f2bf(x1.y);
            a0[6]=(short)f2bf(x1.z); a0[7]=(short)f2bf(x1.w);
            a1[0]=(short)f2bf(x2.x); a1[1]=(short)f2bf(x2.y);
            a1[2]=(short)f2bf(x2.z); a1[3]=(short)f2bf(x2.w);
            a1[4]=(short)f2bf(x3.x); a1[5]=(short)f2bf(x3.y);
            a1[6]=(short)f2bf(x3.z); a1[7]=(short)f2bf(x3.w);
        } else {
            const u16* xr = (const u16*)Xa + (size_t)(r0 + ln) * 64;
            a0 = *(const frag_ab*)(xr + q * 8);
            a1 = *(const frag_ab*)(xr + 32 + q * 8);
        }
        f32x4 acc[4];
#pragma unroll
        for (int nt = 0; nt < 4; ++nt) {
            acc[nt] = (f32x4){0.f, 0.f, 0.f, 0.f};
            acc[nt] = __builtin_amdgcn_mfma_f32_16x16x32_bf16(a0, bfr[nt][0], acc[nt], 0, 0, 0);
            acc[nt] = __builtin_amdgcn_mfma_f32_16x16x32_bf16(a1, bfr[nt][1], acc[nt], 0, 0, 0);
        }
        float di[4];
#pragma unroll
        for (int reg = 0; reg < 4; ++reg)
            di[reg] = rsqrtf((float)(cnt[r0 + q * 4 + reg] + 1));
#pragma unroll
        for (int nt = 0; nt < 4; ++nt)
#pragma unroll
            for (int reg = 0; reg < 4; ++reg)
                T[(size_t)(r0 + q * 4 + reg) * 64 + nt * 16 + ln] =
                    f2bf(acc[nt][reg] * di[reg]);
    }
}

__global__ void __launch_bounds__(256) k_gemm1(
        const float* __restrict__ X, const u16* __restrict__ Wb,
        const int* __restrict__ cnt, u16* __restrict__ T) {
    gemm_body<true>(X, Wb, cnt, T);
}
__global__ void __launch_bounds__(256) k_gemm2(
        const u16* __restrict__ Ab, const u16* __restrict__ Wb,
        const int* __restrict__ cnt, u16* __restrict__ T) {
    gemm_body<false>(Ab, Wb, cnt, T);
}

// ------------------- gather (R10-proven pair-fused, 8-deep) ---------------
// Wave owns a CONTIGUOUS chunk of node pairs; per pair, both buckets form
// one logical stream routed to accA/accB by boundary compare. 8-deep
// batches (the VGPR~20 pipelined shape — 16-deep serializes, R6). Invalid
// slots masked to hot self row. POOL: run-length pooling (~1 flush/lane).
template <bool POOL>
__device__ __forceinline__ void gather_body(
        const u16* __restrict__ T, const int* __restrict__ col,
        const int* __restrict__ cnt,
        const float* __restrict__ b, const float* __restrict__ g,
        const float* __restrict__ be, const float* __restrict__ m,
        const float* __restrict__ v, const int* __restrict__ batch,
        u16* __restrict__ Ab, float* __restrict__ pooled) {
    int lane = threadIdx.x & 63;
    int wave = blockIdx.x * 4 + (threadIdx.x >> 6);
    int nwaves = gridDim.x * 4;
    float sc = g[lane] * rsqrtf(v[lane] + BN_EPS_C);
    float c0 = (b[lane] - m[lane]) * sc + be[lane];
    const int npairs = N_NODES_C / 2;
    const int chunk = (npairs + nwaves - 1) / nwaves;
    int p0 = wave * chunk;
    int p1 = p0 + chunk; if (p1 > npairs) p1 = npairs;
    float psum = 0.f; int curg = -1;
    for (int p = p0; p < p1; ++p) {
        int rA = __builtin_amdgcn_readfirstlane(p * 2);
        int rB = rA + 1;
        int degA = cnt[rA]; if (degA > CAP_C) degA = CAP_C;
        int degB = cnt[rB]; if (degB > CAP_C) degB = CAP_C;
        int tot = degA + degB;
        const int* cbA = col + (size_t)rA * CAP_C;
        const int* cbB = col + (size_t)rB * CAP_C;
        float accA = bf2f(T[(size_t)rA * 64 + lane]);  // self (dinv in T)
        float accB = bf2f(T[(size_t)rB * 64 + lane]);
        for (int j = 0; j < tot; j += 8) {
            int idx[8];
#pragma unroll
            for (int k = 0; k < 8; ++k) {
                int jj = j + k;
                bool valid = jj < tot;
                bool isB = jj >= degA;
                const int* cb = isB ? cbB : cbA;
                int o = isB ? (jj - degA) : jj;
                int c = cb[valid ? o : 0];   // in-bounds addr; value masked next
                idx[k] = valid ? c : rA;     // tail -> hot self row
            }
            float tv[8];
#pragma unroll
            for (int k = 0; k < 8; ++k)
                tv[k] = bf2f(T[(size_t)idx[k] * 64 + lane]);
#pragma unroll
            for (int k = 0; k < 8; ++k) {
                int jj = j + k;
                accA += (jj < degA) ? tv[k] : 0.f;
                accB += (jj >= degA && jj < tot) ? tv[k] : 0.f;
            }
        }
        float drA = rsqrtf((float)(degA + 1));
        float drB = rsqrtf((float)(degB + 1));
        float valA = fmaxf(fmaf(accA * drA, sc, c0), 0.f);
        float valB = fmaxf(fmaf(accB * drB, sc, c0), 0.f);
        if (POOL) {
            int gA = batch[rA], gB = batch[rB];
            if (gA != curg) {
                if (curg >= 0) atomicAdd(&pooled[curg * 64 + lane], psum);
                curg = gA; psum = 0.f;
            }
            psum += valA;
            if (gB != curg) {
                atomicAdd(&pooled[curg * 64 + lane], psum);
                curg = gB; psum = 0.f;
            }
            psum += valB;
        } else {
            Ab[(size_t)rA * 64 + lane] = f2bf(valA);
            Ab[(size_t)rB * 64 + lane] = f2bf(valB);
        }
    }
    if (POOL && curg >= 0) atomicAdd(&pooled[curg * 64 + lane], psum);
}

__global__ void __launch_bounds__(256) k_gather1(
        const u16* __restrict__ T, const int* __restrict__ col,
        const int* __restrict__ cnt,
        const float* __restrict__ b, const float* __restrict__ g,
        const float* __restrict__ be, const float* __restrict__ m,
        const float* __restrict__ v, u16* __restrict__ Ab) {
    gather_body<false>(T, col, cnt, b, g, be, m, v, nullptr, Ab, nullptr);
}

__global__ void __launch_bounds__(256) k_gather2(
        const u16* __restrict__ T, const int* __restrict__ col,
        const int* __restrict__ cnt,
        const float* __restrict__ b, const float* __restrict__ g,
        const float* __restrict__ be, const float* __restrict__ m,
        const float* __restrict__ v, const int* __restrict__ batch,
        float* __restrict__ pooled) {
    gather_body<true>(T, col, cnt, b, g, be, m, v, batch, nullptr, pooled);
}

// ----------------------------- classifier --------------------------------
__global__ void k_final(const float* __restrict__ pooled, const int* __restrict__ batch,
                        const float* __restrict__ Wc, const float* __restrict__ bc,
                        float* __restrict__ out) {
    __shared__ float sp[64 * 65];
    __shared__ int sub[64];
    int t = threadIdx.x;  // 256 threads
    for (int i = t; i < 4096; i += 256) sp[(i >> 6) * 65 + (i & 63)] = pooled[i];
    if (t < 64) {
        int lo = 0, hi = N_NODES_C;
        while (lo < hi) { int mid = (lo + hi) >> 1; if (batch[mid] > t) hi = mid; else lo = mid + 1; }
        sub[t] = lo;  // first index with batch > t
    }
    __syncthreads();
    if (t < 64) {
        int gi = t;
        int lb = gi ? sub[gi - 1] : 0;
        int cntg = sub[gi] - lb;
        float inv = 1.0f / fmaxf((float)cntg, 1.0f);
        float a0 = 0.f, a1 = 0.f;
#pragma unroll 8
        for (int f = 0; f < 64; ++f) {
            float p = sp[gi * 65 + f];
            a0 = fmaf(p, Wc[f * 2 + 0], a0);
            a1 = fmaf(p, Wc[f * 2 + 1], a1);
        }
        out[gi * 2 + 0] = a0 * inv + bc[0];
        out[gi * 2 + 1] = a1 * inv + bc[1];
    }
}

extern "C" void kernel_launch(void* const* d_in, const int* in_sizes, int n_in,
                              void* d_out, int out_size, void* d_ws, size_t ws_size,
                              hipStream_t stream) {
    const float* x    = (const float*)d_in[0];
    const int*   ei   = (const int*)d_in[1];
    const int*   batch= (const int*)d_in[2];
    const float* W1 = (const float*)d_in[3];
    const float* b1 = (const float*)d_in[4];
    const float* g1 = (const float*)d_in[5];
    const float* be1= (const float*)d_in[6];
    const float* m1 = (const float*)d_in[7];
    const float* v1 = (const float*)d_in[8];
    const float* W2 = (const float*)d_in[9];
    const float* b2 = (const float*)d_in[10];
    const float* g2 = (const float*)d_in[11];
    const float* be2= (const float*)d_in[12];
    const float* m2 = (const float*)d_in[13];
    const float* v2 = (const float*)d_in[14];
    const float* Wc = (const float*)d_in[15];
    const float* bc = (const float*)d_in[16];
    float* out = (float*)d_out;

    char* ws = (char*)d_ws;
    size_t off = 0;
    auto alloc = [&](size_t bytes) {
        size_t o = off;
        off = (off + bytes + 511) & ~(size_t)511;
        return o;
    };
    size_t o_cnt   = alloc((size_t)N_NODES_C * 4);
    size_t o_pool  = alloc((size_t)NUM_GRAPHS_C * D_C * 4);
    size_t o_gcur  = alloc(8 * 4);
    size_t zero_bytes = off;  // [cnt | pooled | gcur] zeroed each call
    size_t o_col   = alloc((size_t)N_NODES_C * CAP_C * 4 + 1024);   // 25.6 MB
    size_t o_seg   = alloc((size_t)NPASS_C * CAPSEG_C * 8);          // 10.2 MB
    size_t o_wb1   = alloc(4096 * 2);
    size_t o_wb2   = alloc(4096 * 2);
    size_t o_t     = alloc((size_t)N_NODES_C * D_C * 2);  // bf16 node-major
    size_t o_ab    = alloc((size_t)N_NODES_C * D_C * 2);  // bf16 node-major
    (void)ws_size; (void)in_sizes; (void)n_in; (void)out_size;

    int*   cnt    = (int*)(ws + o_cnt);
    float* pooled = (float*)(ws + o_pool);
    int*   gcur   = (int*)(ws + o_gcur);
    int*   col    = (int*)(ws + o_col);
    int2*  seg    = (int2*)(ws + o_seg);
    u16*   Wb1    = (u16*)(ws + o_wb1);
    u16*   Wb2    = (u16*)(ws + o_wb2);
    u16*   T      = (u16*)(ws + o_t);
    u16*   Ab     = (u16*)(ws + o_ab);

    const int* srcp = ei;
    const int* dstp = ei + N_EDGES_C;

    hipMemsetAsync(ws, 0, zero_bytes, stream);

    int ablocks = 512 + 1;  // partition blocks + 1 W-prep block
    int bblocks = 1024;     // 128 chunks x 8 XCD-swizzled ranges
    int gblocks = 2048;     // 8192 persistent waves
    int mblocks = 1563;     // 6252 waves: one 16-row strip each
    k_part<<<ablocks, 256, 0, stream>>>(srcp, dstp, gcur, seg, W1, W2, Wb1, Wb2);
    k_bucket<<<bblocks, 256, 0, stream>>>(seg, gcur, cnt, col);

    k_gemm1<<<mblocks, 256, 0, stream>>>(x, Wb1, cnt, T);
    k_gather1<<<gblocks, 256, 0, stream>>>(T, col, cnt, b1, g1, be1, m1, v1, Ab);
    k_gemm2<<<mblocks, 256, 0, stream>>>(Ab, Wb2, cnt, T);
    k_gather2<<<gblocks, 256, 0, stream>>>(T, col, cnt, b2, g2, be2, m2, v2,
                                           batch, pooled);
    k_final<<<1, 256, 0, stream>>>(pooled, batch, Wc, bc, out);
}